// Round 1
// baseline (2152.088 us; speedup 1.0000x reference)
//
#include <hip/hip_runtime.h>

// ============================================================================
// GeneratorBilinear: fused PGA(3,0,1) bilinear block on MI355X (gfx950).
// Round 4: occupancy attack.
//   - One thread per (point, channel-pair): h_l/h_r computed in REGISTERS,
//     bilinear (gp/join) in registers -> only the 16-float result hits LDS.
//   - hs tile (98KB) eliminated: LDS 151KB -> 49.4KB => 3 blocks/CU
//     (12 waves/CU, 3/SIMD) vs previous 1 block (4 waves/CU).
//   - Uniform work per task (no e0-blade 2x wave imbalance).
//   - Weights repacked [o][basis 0..8][i]: 9 dwordx4 imm-offset streams/channel,
//     8-lane broadcast within wave.
//   - PTS=8, rows padded to 772 floats: per-p stride = 4 banks -> the 8
//     distinct lane addresses of each ds_read_b128 cover all 32 banks once.
//
// equi_linear decomposition (verified against reference basis construction):
//   out[o,k] = sum_i w[o,i,grade(k)] * x[i,k]
//            + (e0 in k) * sum_i w[o,i,4+grade(k)] * x[i, k\e0]
// (all e0-multiplication basis signs are +1)
// ============================================================================

// ---------------- compile-time PGA tables (mirror reference _mul) -----------
constexpr unsigned char BB[16] = {
  0x0, 0x1, 0x2, 0x4, 0x8,            // (), e0, e1, e2, e3
  0x3, 0x5, 0x9, 0x6, 0xA, 0xC,       // e01,e02,e03,e12,e13,e23
  0x7, 0xB, 0xD, 0xE,                 // e012,e013,e023,e123
  0xF                                 // e0123
};
constexpr int popc4(unsigned x){ return (x&1)+((x>>1)&1)+((x>>2)&1)+((x>>3)&1); }
constexpr int idx_of(unsigned bits){
  int r = 0;
  for (int i = 0; i < 16; ++i) if (BB[i] == bits) r = i;
  return r;
}
// sign from bubble-sorting concat(a,b): (-1)^(# inversions between a and b)
constexpr int reorder_sign(unsigned a, unsigned b){
  int sw = 0;
  for (int g = 0; g < 4; ++g) if (b & (1u<<g)) sw += popc4(a >> (g+1));
  return (sw & 1) ? -1 : 1;
}
struct Tab { signed char s[16][16]; signed char k[16][16]; };
constexpr Tab make_gp(){
  Tab t{};
  for (int i = 0; i < 16; ++i)
    for (int j = 0; j < 16; ++j){
      unsigned a = BB[i], b = BB[j];
      if ((a & b) & 1u) { t.s[i][j] = 0; t.k[i][j] = 0; }    // e0^2 = 0
      else { t.s[i][j] = (signed char)reorder_sign(a,b);      // e1..e3 square +1
             t.k[i][j] = (signed char)idx_of(a ^ b); }
    }
  return t;
}
constexpr int d_idx(int i){ return idx_of(0xFu ^ BB[i]); }
constexpr int d_sgn(int i){ return reorder_sign(BB[i], 0xFu ^ BB[i]); }
// fused join table: undual(wedge(dual(x),dual(y)))  -> j[l] = sum s*x[a]*y[b]
constexpr Tab make_join(){
  Tab t{};
  for (int a = 0; a < 16; ++a)
    for (int b = 0; b < 16; ++b){
      int da = d_idx(a), db = d_idx(b);
      if (BB[da] & BB[db]) { t.s[a][b] = 0; t.k[a][b] = 0; }
      else {
        int ws = reorder_sign(BB[da], BB[db]);
        int m  = idx_of(BB[da] ^ BB[db]);       // wedge result blade
        int l  = idx_of(0xFu ^ BB[m]);          // undual: comp(l) == m
        t.s[a][b] = (signed char)(d_sgn(a) * d_sgn(b) * ws * d_sgn(l));
        t.k[a][b] = (signed char)l;
      }
    }
  return t;
}
constexpr Tab GPT = make_gp();
constexpr Tab JNT = make_join();

struct ITab { int v[16]; };
constexpr ITab make_grade(){ ITab t{}; for (int i=0;i<16;++i) t.v[i]=popc4(BB[i]); return t; }
constexpr ITab make_partner(){ ITab t{}; for (int i=0;i<16;++i) t.v[i]=idx_of(BB[i] & ~1u); return t; }
constexpr ITab make_e0(){ ITab t{}; for (int i=0;i<16;++i) t.v[i]=(BB[i]&1u); return t; }
constexpr ITab GRD = make_grade();
constexpr ITab PRT = make_partner();
constexpr ITab E0T = make_e0();

// ---------------- sizes ------------------------------------------------------
#define NPTS   65536          // B*P = 64*1024
#define CIN    48
#define CH     96             // 2*C_inter
#define COUT   48
#define PTS    8              // points per block
#define XROWF  772            // fp32 elems/point row (768 data + 4 pad -> bank stride 4)
#define WSTR   432            // 9*48 floats per output channel in packed weights

// float4 component by (compile-time) index
__device__ __forceinline__ float f4c(const float4& v, int c){
  return c==0 ? v.x : (c==1 ? v.y : (c==2 ? v.z : v.w));
}

// ---------------- weight prep: fp32 [o][i][9] -> fp32 [o][9][i] -------------
__global__ void prep_weights(const float* __restrict__ wb,
                             const float* __restrict__ wn,
                             float* __restrict__ W1, float* __restrict__ W2){
  int i = blockIdx.x * 256 + threadIdx.x;
  if (i < 9*CH*CIN){                       // 41472
    int o = i / WSTR; int r = i % WSTR; int b = r / CIN; int c = r % CIN;
    W1[i] = wb[(o*CIN + c)*9 + b];
  }
  if (i < 9*COUT*CIN){                     // 20736
    int o = i / WSTR; int r = i % WSTR; int b = r / CIN; int c = r % CIN;
    W2[i] = wn[(o*CIN + c)*9 + b];
  }
}

// ---------------- fused main kernel ------------------------------------------
__global__ __launch_bounds__(256, 3)
void fused_bilinear(const float* __restrict__ x,     // [NPTS][48][16] fp32
                    const float* __restrict__ refp,  // [64][16] fp32
                    const float* __restrict__ W1,    // [96][9][48] fp32
                    const float* __restrict__ W2,    // [48][9][48] fp32
                    float* __restrict__ out){        // [NPTS][48][16] fp32
  __shared__ float xs[PTS * XROWF];   // 24,704 B : x tile, later reused as out staging
  __shared__ float gs[PTS * XROWF];   // 24,704 B : [gp;join] intermediate
                                      // total 49,408 B -> 3 blocks/CU

  const int t  = threadIdx.x;
  const long p0 = (long)blockIdx.x * PTS;

  // ---- stage 0: coalesced fp32 x tile load ----
  for (int c = t; c < PTS * 192; c += 256){            // 192 float4-chunks per point
    int p = c / 192, r = c % 192;
    ((float4*)(xs + p * XROWF))[r] = ((const float4*)(x + (p0 + p) * 768))[r];
  }
  __syncthreads();

  // ---- stage 1+2 fused: per (point, channel-pair) thread ----
  // task tau: p = tau&7, c = tau>>3 in [0,48)
  //   c <  24 : gp  pair (c,      24+c)
  //   c >= 24 : join pair (24+c,  48+c)   (c-24 -> channels 48+cj / 72+cj)
  for (int tau = t; tau < PTS * 48; tau += 256){
    const int p = tau & (PTS - 1);
    const int c = tau >> 3;
    const int cl = (c < 24) ? c        : (24 + c);
    const int cr = (c < 24) ? (24 + c) : (48 + c);
    const float* __restrict__ Wl = W1 + cl * WSTR;
    const float* __restrict__ Wr = W1 + cr * WSTR;

    float hl[16], hr[16];
    #pragma unroll
    for (int k = 0; k < 16; ++k){ hl[k] = 0.f; hr[k] = 0.f; }

    #pragma unroll 1
    for (int i0 = 0; i0 < CIN; i0 += 4){
      float4 wl[9], wr[9];
      #pragma unroll
      for (int b = 0; b < 9; ++b){
        wl[b] = *(const float4*)(Wl + b*CIN + i0);   // imm-offset dwordx4, 8-lane bcast
        wr[b] = *(const float4*)(Wr + b*CIN + i0);
      }
      #pragma unroll
      for (int di = 0; di < 4; ++di){
        const float* xi = xs + p * XROWF + (i0 + di) * 16;
        const float4 x0 = *(const float4*)(xi);
        const float4 x1 = *(const float4*)(xi + 4);
        const float4 x2 = *(const float4*)(xi + 8);
        const float4 x3 = *(const float4*)(xi + 12);
        const float xv[16] = {x0.x,x0.y,x0.z,x0.w, x1.x,x1.y,x1.z,x1.w,
                              x2.x,x2.y,x2.z,x2.w, x3.x,x3.y,x3.z,x3.w};
        #pragma unroll
        for (int k = 0; k < 16; ++k){
          const float xk = xv[k];
          hl[k] += f4c(wl[GRD.v[k]], di) * xk;
          hr[k] += f4c(wr[GRD.v[k]], di) * xk;
        }
        #pragma unroll
        for (int k = 0; k < 16; ++k){
          if (E0T.v[k]){
            const float xp = xv[PRT.v[k]];
            hl[k] += f4c(wl[4 + GRD.v[k]], di) * xp;
            hr[k] += f4c(wr[4 + GRD.v[k]], di) * xp;
          }
        }
      }
    }

    // bilinear in registers
    float oo[16];
    #pragma unroll
    for (int k = 0; k < 16; ++k) oo[k] = 0.f;
    if (c < 24){
      #pragma unroll
      for (int i = 0; i < 16; ++i)
        #pragma unroll
        for (int j = 0; j < 16; ++j){
          const int s = GPT.s[i][j];
          if (s > 0)      oo[GPT.k[i][j]] += hl[i]*hr[j];
          else if (s < 0) oo[GPT.k[i][j]] -= hl[i]*hr[j];
        }
    } else {
      #pragma unroll
      for (int i = 0; i < 16; ++i)
        #pragma unroll
        for (int j = 0; j < 16; ++j){
          const int s = JNT.s[i][j];
          if (s > 0)      oo[JNT.k[i][j]] += hl[i]*hr[j];
          else if (s < 0) oo[JNT.k[i][j]] -= hl[i]*hr[j];
        }
      const float rps = refp[(int)((p0 + p) >> 10) * 16 + 15];
      #pragma unroll
      for (int k = 0; k < 16; ++k) oo[k] *= rps;
    }
    float* gp_ = gs + p * XROWF + c * 16;
    *(float4*)(gp_ + 0)  = make_float4(oo[0], oo[1], oo[2], oo[3]);
    *(float4*)(gp_ + 4)  = make_float4(oo[4], oo[5], oo[6], oo[7]);
    *(float4*)(gp_ + 8)  = make_float4(oo[8], oo[9], oo[10],oo[11]);
    *(float4*)(gp_ + 12) = make_float4(oo[12],oo[13],oo[14],oo[15]);
  }
  __syncthreads();   // gs visible; xs dead -> reuse as out staging

  // ---- stage 3: out = equi_linear(g, w_next), per (point, out-channel) ----
  float* outS = xs;
  for (int tau = t; tau < PTS * 48; tau += 256){
    const int p = tau & (PTS - 1);
    const int o = tau >> 3;
    const float* __restrict__ Wo = W2 + o * WSTR;

    float acc[16];
    #pragma unroll
    for (int k = 0; k < 16; ++k) acc[k] = 0.f;

    #pragma unroll 1
    for (int c0 = 0; c0 < CIN; c0 += 4){
      float4 w[9];
      #pragma unroll
      for (int b = 0; b < 9; ++b) w[b] = *(const float4*)(Wo + b*CIN + c0);
      #pragma unroll
      for (int dc = 0; dc < 4; ++dc){
        const float* gi = gs + p * XROWF + (c0 + dc) * 16;
        const float4 g0 = *(const float4*)(gi);
        const float4 g1 = *(const float4*)(gi + 4);
        const float4 g2 = *(const float4*)(gi + 8);
        const float4 g3 = *(const float4*)(gi + 12);
        const float gv[16] = {g0.x,g0.y,g0.z,g0.w, g1.x,g1.y,g1.z,g1.w,
                              g2.x,g2.y,g2.z,g2.w, g3.x,g3.y,g3.z,g3.w};
        #pragma unroll
        for (int k = 0; k < 16; ++k)
          acc[k] += f4c(w[GRD.v[k]], dc) * gv[k];
        #pragma unroll
        for (int k = 0; k < 16; ++k){
          if (E0T.v[k])
            acc[k] += f4c(w[4 + GRD.v[k]], dc) * gv[PRT.v[k]];
        }
      }
    }
    float* op_ = outS + p * XROWF + o * 16;
    *(float4*)(op_ + 0)  = make_float4(acc[0], acc[1], acc[2], acc[3]);
    *(float4*)(op_ + 4)  = make_float4(acc[4], acc[5], acc[6], acc[7]);
    *(float4*)(op_ + 8)  = make_float4(acc[8], acc[9], acc[10],acc[11]);
    *(float4*)(op_ + 12) = make_float4(acc[12],acc[13],acc[14],acc[15]);
  }
  __syncthreads();

  // ---- stage 4: coalesced fp32 store ----
  for (int c = t; c < PTS * 192; c += 256){
    int p = c / 192, r = c % 192;
    ((float4*)(out + (p0 + p) * 768))[r] = ((const float4*)(outS + p * XROWF))[r];
  }
}

// ---------------- launch -----------------------------------------------------
extern "C" void kernel_launch(void* const* d_in, const int* in_sizes, int n_in,
                              void* d_out, int out_size, void* d_ws, size_t ws_size,
                              hipStream_t stream){
  (void)in_sizes; (void)n_in; (void)out_size; (void)ws_size;
  const float* hidden = (const float*)d_in[0];   // [64,1024,48,16] fp32
  const float* refp   = (const float*)d_in[1];   // [64,1,1,16]     fp32
  const float* wbili  = (const float*)d_in[2];   // [96,48,9]       fp32
  const float* wnext  = (const float*)d_in[3];   // [48,48,9]       fp32
  float* outp = (float*)d_out;                   // [64,1024,48,16] fp32

  float* W1 = (float*)d_ws;                 // [96][9][48] fp32 = 165,888 B
  float* W2 = W1 + 9*CH*CIN;                // [48][9][48] fp32 =  82,944 B

  prep_weights<<<162, 256, 0, stream>>>(wbili, wnext, W1, W2);
  fused_bilinear<<<NPTS/PTS, 256, 0, stream>>>(hidden, refp, W1, W2, outp);
}